// Round 12
// baseline (26.735 us; speedup 1.0000x reference)
//
#include <hip/hip_runtime.h>

// PyQHamiltonianEvolution: N_QUBITS=20, SUPPORT=(3,8,15), BATCH=8, DIM=8
// state layout (2,)*20 + (8,) row-major, batch innermost.
// element-address support bits: q3 -> bit19 (524288), q8 -> bit14 (16384),
// q15 -> bit7 (128); batch = bits 0-2. Output = f32 REAL part, 2^23 elems.
//
// Round 12: LONG-STREAM restructure. Each block runs 4 iterations; its 12
// global streams (4 c-combos x {re,im,out}) advance 2KB contiguously per
// iteration = 8KB sequential per stream (engage L2 stream prefetch).
// Next-iter loads are register-staged early (issue under compute).
// 1024 blocks x 512 threads = 4 blocks/CU = 32 waves/CU (max occupancy).
//
// addr bits: [l:0-6][s15:7][rb:8][iter:9-10][blk:11-13,15-18,20-22][c:14,19]

#define CQ3 524288u
#define CQ8 16384u

__global__ void expm_kernel(const float* __restrict__ h_real,
                            const float* __restrict__ h_imag,
                            const float* __restrict__ t_g,
                            float* __restrict__ U)     // [ (i*8+b)*16 + 2o (+1) ]
{
    __shared__ float Tre[64], Tim[64], Mre[64], Mim[64], Ere[64], Eim[64];

    const int b = blockIdx.x;          // batch
    const int e = threadIdx.x;         // matrix entry, one per lane
    const int o = e >> 3, i = e & 7;

    const float sc  = t_g[b] * (1.0f / 32.0f);   // M = (-i t H) / 2^5
    const float mre =  sc * h_imag[e];
    const float mim = -sc * h_real[e];

    Mre[e] = mre; Mim[e] = mim;
    Tre[e] = mre; Tim[e] = mim;
    float are = (o == i ? 1.f : 0.f) + mre;      // E = I + M
    float aim = mim;
    __syncthreads();

    for (int k = 2; k <= 10; ++k) {    // T = T*M/k ; E += T
        float sre = 0.f, sim = 0.f;
        #pragma unroll
        for (int j = 0; j < 8; ++j) {
            const float tre = Tre[o * 8 + j], tim = Tim[o * 8 + j];
            const float qre = Mre[j * 8 + i], qim = Mim[j * 8 + i];
            sre += tre * qre - tim * qim;
            sim += tre * qim + tim * qre;
        }
        const float inv = 1.0f / (float)k;
        sre *= inv; sim *= inv;
        __syncthreads();
        Tre[e] = sre; Tim[e] = sim;
        are += sre; aim += sim;
        __syncthreads();
    }

    Ere[e] = are; Eim[e] = aim;
    __syncthreads();

    for (int sq = 0; sq < 5; ++sq) {   // E = E*E
        float sre = 0.f, sim = 0.f;
        #pragma unroll
        for (int j = 0; j < 8; ++j) {
            const float xre = Ere[o * 8 + j], xim = Eim[o * 8 + j];
            const float yre = Ere[j * 8 + i], yim = Eim[j * 8 + i];
            sre += xre * yre - xim * yim;
            sim += xre * yim + xim * yre;
        }
        __syncthreads();
        if (sq < 4) {
            Ere[e] = sre; Eim[e] = sim;
            __syncthreads();
        } else {
            U[(i * 8 + b) * 16 + 2 * o]     = sre;   // column-major for apply
            U[(i * 8 + b) * 16 + 2 * o + 1] = sim;
        }
    }
}

__global__ __launch_bounds__(512, 8) void apply_kernel(
        const float* __restrict__ sre_g,
        const float* __restrict__ sim_g,
        const float4* __restrict__ U4,   // 256 float4 = [i][b][16 floats]
        float* __restrict__ out)
{
    __shared__ alignas(16) float inRe[4 * 512];
    __shared__ alignas(16) float inIm[4 * 512];
    __shared__ alignas(16) float outL[4 * 512];
    // U: [i][b] slots, stride 20 floats (banks b*20 mod 32 all distinct ->
    // conflict-free broadcast reads, 16B-aligned).
    __shared__ alignas(16) float uL[8 * 8 * 20];

    const int tid = threadIdx.x;           // 0..511
    const unsigned B = blockIdx.x;         // 0..1023
    const unsigned addr_hi = ((B & 0x007u) << 11)
                           | ((B & 0x078u) << 12)
                           | ((B & 0x380u) << 13);

    // staging role: c-chunk (tid>>7), float4 index j within chunk
    const int c = tid >> 7;                // 0..3 = (q3<<1)|q8
    const int j = tid & 127;
    const unsigned cOff = ((c & 2) ? CQ3 : 0u) + ((c & 1) ? CQ8 : 0u);
    const unsigned gchunk = addr_hi + cOff;   // + n*512 + j*4

    // iteration-0 loads FIRST (memory flowing before anything else)
    float4 rRe = *(const float4*)(sre_g + gchunk + j * 4);
    float4 rIm = *(const float4*)(sim_g + gchunk + j * 4);

    // stage U (threads 0-255)
    if (tid < 256) {
        const float4 u = U4[tid];          // tid = (i*8+b)*4 + k
        const int ib = tid >> 2, k = tid & 3;
        *(float4*)&uL[ib * 20 + k * 4] = u;
    }

    // compute role: slot (l, rb), output half h (o in [4h, 4h+4))
    const int l  = tid & 127;
    const int rb = (tid >> 7) & 1;
    const int h  = tid >> 8;
    const int b  = l & 7;
    const int xbase = rb * 256 + l;

    #pragma unroll
    for (int n = 0; n < 4; ++n) {
        // write staged regs to LDS
        *(float4*)&inRe[c * 512 + j * 4] = rRe;
        *(float4*)&inIm[c * 512 + j * 4] = rIm;
        __syncthreads();                   // in-LDS (and uL on n=0) ready

        // early-issue next iteration's loads (hide under compute)
        if (n < 3) {
            rRe = *(const float4*)(sre_g + gchunk + (n + 1) * 512 + j * 4);
            rIm = *(const float4*)(sim_g + gchunk + (n + 1) * 512 + j * 4);
        }

        // compute this thread's 4 outputs for slot (l, rb)
        float a0 = 0.f, a1 = 0.f, a2 = 0.f, a3 = 0.f;
        #pragma unroll
        for (int i = 0; i < 8; ++i) {      // i = (q3<<2)|(q8<<1)|q15
            const int xoff = (i >> 1) * 512 + (i & 1) * 128 + xbase;
            const float xr = inRe[xoff];
            const float xi = inIm[xoff];
            const float4* uv = (const float4*)&uL[(i * 8 + b) * 20];
            const float4 uA = uv[2 * h];       // o = 4h, 4h+1
            const float4 uB = uv[2 * h + 1];   // o = 4h+2, 4h+3
            a0 += uA.x * xr - uA.y * xi;
            a1 += uA.z * xr - uA.w * xi;
            a2 += uB.x * xr - uB.y * xi;
            a3 += uB.z * xr - uB.w * xi;
        }

        // outstage: o -> chunk c'=o>>1, s15'=o&1  (halves write disjoint c')
        const int o0 = 4 * h;
        outL[((o0    ) >> 1) * 512 + ((o0    ) & 1) * 128 + xbase] = a0;
        outL[((o0 + 1) >> 1) * 512 + ((o0 + 1) & 1) * 128 + xbase] = a1;
        outL[((o0 + 2) >> 1) * 512 + ((o0 + 2) & 1) * 128 + xbase] = a2;
        outL[((o0 + 3) >> 1) * 512 + ((o0 + 3) & 1) * 128 + xbase] = a3;
        __syncthreads();                   // outL ready; in-LDS free

        // contiguous store (stream advance +2KB per iter)
        *(float4*)(out + gchunk + n * 512 + j * 4) =
            *(const float4*)&outL[c * 512 + j * 4];
    }
}

extern "C" void kernel_launch(void* const* d_in, const int* in_sizes, int n_in,
                              void* d_out, int out_size, void* d_ws, size_t ws_size,
                              hipStream_t stream) {
    const float* state_real = (const float*)d_in[0];
    const float* state_imag = (const float*)d_in[1];
    const float* h_real     = (const float*)d_in[2];
    const float* h_imag     = (const float*)d_in[3];
    const float* t          = (const float*)d_in[4];

    float* U = (float*)d_ws;   // 1024 floats = 4 KB

    expm_kernel<<<8, 64, 0, stream>>>(h_real, h_imag, t, U);

    // 2^23 elements / 8192 per block = 1024 blocks x 512 threads
    apply_kernel<<<1024, 512, 0, stream>>>(state_real, state_imag,
                                           (const float4*)U, (float*)d_out);
}